// Round 1
// 128.840 us; speedup vs baseline: 1.2651x; 1.2651x over previous
//
#include <hip/hip_runtime.h>

// GCN 2-layer: out = Ahat * relu(Ahat*(X W1)+b1) * W2 + b2
// Ahat = D^-1/2 (A+I) D^-1/2, pull-based CSR aggregation.
// R8: (1) k_agg1 latency fix — uint4 gathers (8 rows/wave-load) + unroll 4
//     gives ~8x in-flight gather bytes/wave (old version: VGPR=16, ~2 uint2
//     loads in flight -> 1.6 TB/s). (2) k_part and k_gemm1 fused into one
//     fat kernel: part uses only 196 blocks (<196 CUs); gemm blocks fill
//     the idle CUs for free. dtype-detect folded into each part block,
//     bptr holds pure counts (memset 0). (3) bucket-base scan folded into
//     k_bucket (redundant 128-entry LDS scan/block). (4) k_agg2 at 4
//     nodes/wave (avg degree 16 left 75% lanes idle).

#define D_IN 64
#define NBBITS 10          // 1024 nodes per bucket
#define NBK_PAD 128        // padded bucket count (N=100K -> 98 real buckets)
#define PCH 8192           // edges per part block
#define BCAP 16384         // LDS srcA stage capacity per bucket
#define BCAPE 24576        // padded ebuf capacity per bucket (mean 16.3K, sd 128)

// ---- bf16 helpers (RN-even) ----
__device__ __forceinline__ float b2f(unsigned short u) {
    unsigned v = ((unsigned)u) << 16;
    float f;
    __builtin_memcpy(&f, &v, 4);
    return f;
}
__device__ __forceinline__ unsigned short f2b(float f) {
    unsigned u;
    __builtin_memcpy(&u, &f, 4);
    u += 0x7FFFu + ((u >> 16) & 1u);
    return (unsigned short)(u >> 16);
}

// edge_index may arrive as int64 (reference dtype) or int32 (harness note).
// int64 little-endian with values < 2^31 has all-zero odd 32-bit words.
__device__ __forceinline__ int edge_val(const int* __restrict__ p, int f64, long pos) {
    return f64 ? p[2 * pos] : p[pos];
}

// Fat kernel: blocks [0, nPart) do the edge counting-sort partition;
// blocks [nPart, grid) do H1 = bf16(X @ W1). The gemm is independent of the
// edge pipeline, so it hides entirely under the latency-bound part phase.
__global__ __launch_bounds__(256, 4) void k_part_gemm(
        const int* __restrict__ ep, int* __restrict__ bptr,
        unsigned* __restrict__ ebuf,
        const float* __restrict__ x, const float* __restrict__ W,
        unsigned short* __restrict__ H, int E, int N, int nPart) {
    __shared__ __align__(16) char smraw[34816];
    int tid = threadIdx.x;

    if (blockIdx.x < nPart) {
        // ---------------- partition path ----------------
        int* hist  = (int*)smraw;                 // [128]
        int* lofs  = hist + NBK_PAD;              // [128]
        int* gbase = lofs + NBK_PAD;              // [128]
        int* fsh   = gbase + NBK_PAD;             // [1] (+3 pad)
        unsigned* stage = (unsigned*)(fsh + 4);   // [PCH], offset 1552, 16B-aligned

        if (tid < NBK_PAD) hist[tid] = 0;
        // per-block dtype detect (8 KB redundant read, L2-shared)
        if (tid < 64) {
            int bad = 0;
            for (int i = tid; i < 1024; i += 64)
                if (ep[2 * i + 1] != 0) bad = 1;
            unsigned long long m = __ballot(bad);
            if (tid == 0) fsh[0] = (m == 0ull) ? 1 : 0;   // 1 => int64
        }
        __syncthreads();
        int f = fsh[0];
        long base = (long)blockIdx.x * PCH;
        for (int i = tid; i < PCH; i += 256) {
            long e = base + i;
            if (e < E) {
                int c = edge_val(ep, f, E + e);
                atomicAdd(&hist[c >> NBBITS], 1);
            }
        }
        __syncthreads();
        if (tid < NBK_PAD) lofs[tid] = hist[tid];
        __syncthreads();
        for (int off = 1; off < NBK_PAD; off <<= 1) {
            int t = (tid < NBK_PAD && tid >= off) ? lofs[tid - off] : 0;
            __syncthreads();
            if (tid < NBK_PAD) lofs[tid] += t;
            __syncthreads();
        }
        if (tid < NBK_PAD) { lofs[tid] -= hist[tid]; hist[tid] = 0; }
        __syncthreads();
        for (int i = tid; i < PCH; i += 256) {
            long e = base + i;
            if (e < E) {
                int c = edge_val(ep, f, E + e);
                int r = edge_val(ep, f, e);
                int b = c >> NBBITS;
                int pos = lofs[b] + atomicAdd(&hist[b], 1);
                stage[pos] = (unsigned)r | ((unsigned)(c & ((1 << NBBITS) - 1)) << 17);
            }
        }
        __syncthreads();
        // bptr is a pure count array (memset 0); append offset is count-based
        if (tid < NBK_PAD && hist[tid]) gbase[tid] = atomicAdd(&bptr[tid], hist[tid]);
        __syncthreads();
        int wid = tid >> 6, lane = tid & 63;
        for (int b = wid; b < NBK_PAD; b += 4) {
            int c = hist[b];
            if (c == 0) continue;
            int lo = lofs[b], go = gbase[b];
            unsigned* dst = ebuf + (size_t)b * BCAPE + go;
            for (int j = lane; j < c; j += 64) dst[j] = stage[lo + j];
        }
    } else {
        // ---------------- gemm path: H1 = bf16(X @ W1) ----------------
        float* Ws = (float*)smraw;                // [64*64]
        float* Xs = (float*)(smraw + 16384);      // [32*68]
        int lane = tid & 63;
        int wv = tid >> 6;                        // wave 0..3
        for (int i = tid; i < 64 * 64; i += 256) Ws[i] = W[i];

        int bid = blockIdx.x - nPart;
        int ngb = gridDim.x - nPart;
        int ntiles = (N + 31) >> 5;
        for (int tile = bid; tile < ntiles; tile += ngb) {
            int rr = tid >> 4, c4 = tid & 15;     // rr 0..15; stage rr and rr+16
            int g0 = (tile << 5) + rr;
            int g1 = g0 + 16;
            float4 v0 = make_float4(0.f, 0.f, 0.f, 0.f);
            float4 v1 = make_float4(0.f, 0.f, 0.f, 0.f);
            if (g0 < N) v0 = *(const float4*)(x + (size_t)g0 * 64 + c4 * 4);
            if (g1 < N) v1 = *(const float4*)(x + (size_t)g1 * 64 + c4 * 4);
            __syncthreads();            // protects Ws (1st iter) + Xs reuse
            *(float4*)(&Xs[rr * 68 + c4 * 4]) = v0;
            *(float4*)(&Xs[(rr + 16) * 68 + c4 * 4]) = v1;
            __syncthreads();
            float acc[8];
            #pragma unroll
            for (int r = 0; r < 8; ++r) acc[r] = 0.f;
            int rbase = wv * 8;
            #pragma unroll 4
            for (int k4 = 0; k4 < 16; ++k4) {
                float w0 = Ws[(4 * k4 + 0) * 64 + lane];
                float w1 = Ws[(4 * k4 + 1) * 64 + lane];
                float w2 = Ws[(4 * k4 + 2) * 64 + lane];
                float w3 = Ws[(4 * k4 + 3) * 64 + lane];
                #pragma unroll
                for (int r = 0; r < 8; ++r) {
                    float4 xq = *(const float4*)(&Xs[(rbase + r) * 68 + k4 * 4]);
                    acc[r] = fmaf(xq.x, w0, acc[r]);
                    acc[r] = fmaf(xq.y, w1, acc[r]);
                    acc[r] = fmaf(xq.z, w2, acc[r]);
                    acc[r] = fmaf(xq.w, w3, acc[r]);
                }
            }
            int row0 = (tile << 5) + rbase;
            #pragma unroll
            for (int r = 0; r < 8; ++r) {
                int row = row0 + r;
                if (row < N) H[(size_t)row * 64 + lane] = f2b(acc[r]);
            }
        }
    }
}

// per-bucket exact CSR: bucket-base scan (folded from old k_bscan2), degree
// hist, block scan -> offs/dinv, LDS slot assignment, srcA staged in LDS.
__global__ __launch_bounds__(1024) void k_bucket(const unsigned* __restrict__ ebuf,
                                                 const int* __restrict__ bptr,
                                                 int* __restrict__ offs,
                                                 float* __restrict__ dinv,
                                                 int* __restrict__ srcA, int N, int E) {
    __shared__ int hist[1024], escan[1024], wsum[16];
    __shared__ int bco[NBK_PAD];
    __shared__ int stage[BCAP];
    int tid = threadIdx.x, b = blockIdx.x;
    int lane = tid & 63, wid = tid >> 6;
    hist[tid] = 0;
    // redundant per-block exclusive scan of the 128 bucket counts
    if (tid < NBK_PAD) {
        int c = bptr[tid];
        int s = c;
        #pragma unroll
        for (int off = 1; off < 64; off <<= 1) {
            int t = __shfl(s, lane - off);
            if (lane >= off) s += t;
        }
        if (lane == 63) wsum[wid] = s;
        bco[tid] = s - c;               // exclusive within wave
    }
    if (tid == 0 && b == 0) offs[N] = E;
    __syncthreads();
    if (tid >= 64 && tid < NBK_PAD) bco[tid] += wsum[0];
    __syncthreads();

    int rbase = b * BCAPE;              // padded read region
    int lo = bco[b];                    // compact write base
    int m = bptr[b];                    // exact count
    for (int i = tid; i < m; i += 1024) {
        unsigned w = ebuf[rbase + i];
        atomicAdd(&hist[w >> 17], 1);
    }
    __syncthreads();
    int v = hist[tid];
    int s = v;
    #pragma unroll
    for (int off = 1; off < 64; off <<= 1) {
        int t = __shfl(s, lane - off);
        if (lane >= off) s += t;
    }
    if (lane == 63) wsum[wid] = s;
    __syncthreads();
    if (tid < 16) {
        int xv = wsum[tid];
        int ss = xv;
        #pragma unroll
        for (int off = 1; off < 16; off <<= 1) {
            int t = __shfl(ss, lane - off);
            if (lane >= off) ss += t;
        }
        wsum[tid] = ss - xv;            // exclusive among wave sums
    }
    __syncthreads();
    int excl = s - v + wsum[wid];
    escan[tid] = excl;
    int g = (b << NBBITS) + tid;
    if (g < N) {
        offs[g] = lo + excl;
        dinv[g] = rsqrtf((float)(v + 1));   // +1 self-loop
    }
    __syncthreads();
    for (int i = tid; i < m; i += 1024) {
        unsigned w = ebuf[rbase + i];
        int lc = w >> 17;
        int src = (int)(w & 0x1FFFFu);
        int sl = escan[lc] + atomicSub(&hist[lc], 1) - 1;
        if (sl < BCAP) stage[sl] = src;
        else srcA[lo + sl] = src;       // statistically-cold overflow path
    }
    __syncthreads();
    int mm = min(m, BCAP);
    for (int i = tid; i < mm; i += 1024) srcA[lo + i] = stage[i];
}

// Layer-1 aggregation: wave per node, uint4 gathers (16B/lane, 8 feature
// bf16s), 8 lanes/row => 8 neighbor rows in flight per wave-load, unroll 4
// => up to 4 KB of gathers outstanding per wave (latency fix). Fused with
// relu, bias, and the 64->2 GEMM of layer 2. Writes Z=[N,2].
__global__ void k_agg1(const unsigned short* __restrict__ H1,
                       const int* __restrict__ srcA,
                       const float* __restrict__ dinv, const int* __restrict__ offs,
                       const float* __restrict__ b1, const float* __restrict__ W2,
                       float* __restrict__ Z, int N) {
    int wid = (blockIdx.x * blockDim.x + threadIdx.x) >> 6;
    int lane = threadIdx.x & 63;
    if (wid >= N) return;
    int n = wid;
    int sub = lane & 7;                 // feature oct: f = 8*sub .. 8*sub+7
    int par = lane >> 3;                // row parity 0..7
    float dn = dinv[n];
    int base = offs[n];
    int cnt = offs[n + 1] - base;
    float a[8];
    #pragma unroll
    for (int k = 0; k < 8; ++k) a[k] = 0.f;
    for (int chunk = 0; chunk < cnt; chunk += 64) {
        int m = min(64, cnt - chunk);
        int sv = 0; float wv = 0.f;
        if (lane < m) { sv = srcA[base + chunk + lane]; wv = dinv[sv]; }
        #pragma unroll 4
        for (int j = 0; j < m; j += 8) {
            int idx = j + par;
            int src = __shfl(sv, idx);
            float w = __shfl(wv, idx);
            if (idx >= m) { src = 0; w = 0.f; }
            uint4 rv = *(const uint4*)(H1 + (size_t)src * 64 + sub * 8);
            a[0] += w * b2f((unsigned short)(rv.x & 0xFFFFu));
            a[1] += w * b2f((unsigned short)(rv.x >> 16));
            a[2] += w * b2f((unsigned short)(rv.y & 0xFFFFu));
            a[3] += w * b2f((unsigned short)(rv.y >> 16));
            a[4] += w * b2f((unsigned short)(rv.z & 0xFFFFu));
            a[5] += w * b2f((unsigned short)(rv.z >> 16));
            a[6] += w * b2f((unsigned short)(rv.w & 0xFFFFu));
            a[7] += w * b2f((unsigned short)(rv.w >> 16));
        }
    }
    // fold the 8 parity groups: xor 8,16,32 -> every lane holds full sums
    #pragma unroll
    for (int off = 8; off <= 32; off <<= 1) {
        #pragma unroll
        for (int k = 0; k < 8; ++k) a[k] += __shfl_xor(a[k], off);
    }
    // self-loop term (identical in all 8 parity copies -> stays consistent)
    uint4 sv4 = *(const uint4*)(H1 + (size_t)n * 64 + sub * 8);
    a[0] += dn * b2f((unsigned short)(sv4.x & 0xFFFFu));
    a[1] += dn * b2f((unsigned short)(sv4.x >> 16));
    a[2] += dn * b2f((unsigned short)(sv4.y & 0xFFFFu));
    a[3] += dn * b2f((unsigned short)(sv4.y >> 16));
    a[4] += dn * b2f((unsigned short)(sv4.z & 0xFFFFu));
    a[5] += dn * b2f((unsigned short)(sv4.z >> 16));
    a[6] += dn * b2f((unsigned short)(sv4.w & 0xFFFFu));
    a[7] += dn * b2f((unsigned short)(sv4.w >> 16));
    float4 b1a = *(const float4*)(b1 + sub * 8);
    float4 b1b = *(const float4*)(b1 + sub * 8 + 4);
    float h0 = fmaxf(dn * a[0] + b1a.x, 0.f);
    float h1 = fmaxf(dn * a[1] + b1a.y, 0.f);
    float h2 = fmaxf(dn * a[2] + b1a.z, 0.f);
    float h3 = fmaxf(dn * a[3] + b1a.w, 0.f);
    float h4 = fmaxf(dn * a[4] + b1b.x, 0.f);
    float h5 = fmaxf(dn * a[5] + b1b.y, 0.f);
    float h6 = fmaxf(dn * a[6] + b1b.z, 0.f);
    float h7 = fmaxf(dn * a[7] + b1b.w, 0.f);
    const float4* w2p = (const float4*)(W2 + sub * 16);
    float4 w0 = w2p[0], w1 = w2p[1], w2q = w2p[2], w3 = w2p[3];
    float p0 = h0 * w0.x + h1 * w0.z + h2 * w1.x + h3 * w1.z
             + h4 * w2q.x + h5 * w2q.z + h6 * w3.x + h7 * w3.z;
    float p1 = h0 * w0.y + h1 * w0.w + h2 * w1.y + h3 * w1.w
             + h4 * w2q.y + h5 * w2q.w + h6 * w3.y + h7 * w3.w;
    // sum the 8 distinct octs within this parity group
    #pragma unroll
    for (int off = 1; off < 8; off <<= 1) {
        p0 += __shfl_xor(p0, off);
        p1 += __shfl_xor(p1, off);
    }
    if (lane == 0) { Z[n * 2 + 0] = p0; Z[n * 2 + 1] = p1; }
}

// Layer-2 aggregation over Z=[N,2]: 4 nodes per wave (avg degree 16 -> full
// lane utilization), 16 lanes over neighbors per node.
__global__ void k_agg2(const float* __restrict__ Z, const int* __restrict__ srcA,
                       const float* __restrict__ dinv, const int* __restrict__ offs,
                       const float* __restrict__ b2, float* __restrict__ out, int N) {
    int t = blockIdx.x * blockDim.x + threadIdx.x;
    int lane = threadIdx.x & 63;
    int n = (t >> 6) * 4 + (lane >> 4);
    int sl = lane & 15;
    if (n >= N) return;                 // uniform per 16-lane group
    int base = offs[n];
    int cnt = offs[n + 1] - base;
    float a0 = 0.f, a1 = 0.f;
    const float2* Z2 = (const float2*)Z;
    for (int i = sl; i < cnt; i += 16) {
        int src = srcA[base + i];
        float w = dinv[src];
        float2 zv = Z2[src];
        a0 += w * zv.x;
        a1 += w * zv.y;
    }
    #pragma unroll
    for (int off = 8; off > 0; off >>= 1) {
        a0 += __shfl_xor(a0, off);
        a1 += __shfl_xor(a1, off);
    }
    if (sl == 0) {
        float dn = dinv[n];
        float2 zs = Z2[n];
        out[n * 2 + 0] = dn * (a0 + dn * zs.x) + b2[0];
        out[n * 2 + 1] = dn * (a1 + dn * zs.y) + b2[1];
    }
}

extern "C" void kernel_launch(void* const* d_in, const int* in_sizes, int n_in,
                              void* d_out, int out_size, void* d_ws, size_t ws_size,
                              hipStream_t stream) {
    const float* x  = (const float*)d_in[0];
    const int*   ep = (const int*)d_in[1];
    const float* W1 = (const float*)d_in[2];
    const float* b1 = (const float*)d_in[3];
    const float* W2 = (const float*)d_in[4];
    const float* b2 = (const float*)d_in[5];
    float* out = (float*)d_out;

    const int N = in_sizes[0] / D_IN;   // 100000
    const int E = in_sizes[1] / 2;      // 1600000

    char* ws = (char*)d_ws;
    size_t o = 0;
    auto alloc = [&](size_t bytes) {
        size_t r = o;
        o = (o + bytes + 255) & ~(size_t)255;
        return r;
    };
    int*            bptr  = (int*)           (ws + alloc(NBK_PAD * 4));
    float*          dinv  = (float*)         (ws + alloc((size_t)N * 4));
    int*            offs  = (int*)           (ws + alloc((size_t)(N + 1) * 4));
    unsigned*       ebuf  = (unsigned*)      (ws + alloc((size_t)NBK_PAD * BCAPE * 4));
    int*            srcA  = (int*)           (ws + alloc((size_t)E * 4));
    unsigned short* H1    = (unsigned short*)(ws + alloc((size_t)N * 64 * 2));
    float*          Z     = (float*)         (ws + alloc((size_t)N * 2 * 4));

    const int nbk = (N + (1 << NBBITS) - 1) >> NBBITS;   // 98
    const int nPart = (E + PCH - 1) / PCH;               // 196
    const int nGemm = 1024;

    hipMemsetAsync(bptr, 0, NBK_PAD * sizeof(int), stream);
    k_part_gemm<<<nPart + nGemm, 256, 0, stream>>>(ep, bptr, ebuf, x, W1, H1, E, N, nPart);
    k_bucket<<<nbk, 1024, 0, stream>>>(ebuf, bptr, offs, dinv, srcA, N, E);
    k_agg1<<<(N + 3) / 4, 256, 0, stream>>>(H1, srcA, dinv, offs, b1, W2, Z, N);
    k_agg2<<<(N + 15) / 16, 256, 0, stream>>>(Z, srcA, dinv, offs, b2, out, N);
}

// Round 3
// 106.079 us; speedup vs baseline: 1.5366x; 1.2146x over previous
//
#include <hip/hip_runtime.h>

// GCN 2-layer: out = Ahat * relu(Ahat*(X W1)+b1) * W2 + b2
// Ahat = D^-1/2 (A+I) D^-1/2, pull-based CSR aggregation.
// R10: R9 with the ACC8 macro bug fixed (macro param `w` collided with the
//     .w member of uint4 -> rv.w expanded to r0.w0). Now an inline function.
//     k_agg1: 8 nodes/wave, 8-lane groups. Lane s of group g owns features
//     8s..8s+7 of node wid*8+g, private accumulation (no parity fold).
//     Per j0-block: stage 8 (src,dinv) per group, 16 shfl broadcasts, then
//     8 independent uint4 gathers issued before any consume (8-deep MLP;
//     old: ~2 in flight, VGPR=28, 1.5 TB/s latency-bound at mean deg 16).

#define D_IN 64
#define NBBITS 10          // 1024 nodes per bucket
#define NBK_PAD 128        // padded bucket count (N=100K -> 98 real buckets)
#define PCH 8192           // edges per part block
#define BCAP 16384         // LDS srcA stage capacity per bucket
#define BCAPE 24576        // padded ebuf capacity per bucket (mean 16.3K, sd 128)

// ---- bf16 helpers (RN-even) ----
__device__ __forceinline__ float b2f(unsigned short u) {
    unsigned v = ((unsigned)u) << 16;
    float f;
    __builtin_memcpy(&f, &v, 4);
    return f;
}
__device__ __forceinline__ unsigned short f2b(float f) {
    unsigned u;
    __builtin_memcpy(&u, &f, 4);
    u += 0x7FFFu + ((u >> 16) & 1u);
    return (unsigned short)(u >> 16);
}

// edge_index may arrive as int64 (reference dtype) or int32 (harness note).
// int64 little-endian with values < 2^31 has all-zero odd 32-bit words.
__device__ __forceinline__ int edge_val(const int* __restrict__ p, int f64, long pos) {
    return f64 ? p[2 * pos] : p[pos];
}

// accumulate 8 bf16 features (one uint4) scaled by wgt into a[0..7]
__device__ __forceinline__ void acc8(float* a, uint4 rv, float wgt) {
    a[0] = fmaf(wgt, b2f((unsigned short)(rv.x & 0xFFFFu)), a[0]);
    a[1] = fmaf(wgt, b2f((unsigned short)(rv.x >> 16)), a[1]);
    a[2] = fmaf(wgt, b2f((unsigned short)(rv.y & 0xFFFFu)), a[2]);
    a[3] = fmaf(wgt, b2f((unsigned short)(rv.y >> 16)), a[3]);
    a[4] = fmaf(wgt, b2f((unsigned short)(rv.z & 0xFFFFu)), a[4]);
    a[5] = fmaf(wgt, b2f((unsigned short)(rv.z >> 16)), a[5]);
    a[6] = fmaf(wgt, b2f((unsigned short)(rv.w & 0xFFFFu)), a[6]);
    a[7] = fmaf(wgt, b2f((unsigned short)(rv.w >> 16)), a[7]);
}

// Fat kernel: blocks [0, nPart) do the edge counting-sort partition;
// blocks [nPart, grid) do H1 = bf16(X @ W1). The gemm is independent of the
// edge pipeline, so it hides entirely under the latency-bound part phase.
__global__ __launch_bounds__(256, 4) void k_part_gemm(
        const int* __restrict__ ep, int* __restrict__ bptr,
        unsigned* __restrict__ ebuf,
        const float* __restrict__ x, const float* __restrict__ W,
        unsigned short* __restrict__ H, int E, int N, int nPart) {
    __shared__ __align__(16) char smraw[34816];
    int tid = threadIdx.x;

    if (blockIdx.x < nPart) {
        // ---------------- partition path ----------------
        int* hist  = (int*)smraw;                 // [128]
        int* lofs  = hist + NBK_PAD;              // [128]
        int* gbase = lofs + NBK_PAD;              // [128]
        int* fsh   = gbase + NBK_PAD;             // [1] (+3 pad)
        unsigned* stage = (unsigned*)(fsh + 4);   // [PCH], offset 1552, 16B-aligned

        if (tid < NBK_PAD) hist[tid] = 0;
        // per-block dtype detect (8 KB redundant read, L2-shared)
        if (tid < 64) {
            int bad = 0;
            for (int i = tid; i < 1024; i += 64)
                if (ep[2 * i + 1] != 0) bad = 1;
            unsigned long long m = __ballot(bad);
            if (tid == 0) fsh[0] = (m == 0ull) ? 1 : 0;   // 1 => int64
        }
        __syncthreads();
        int f = fsh[0];
        long base = (long)blockIdx.x * PCH;
        for (int i = tid; i < PCH; i += 256) {
            long e = base + i;
            if (e < E) {
                int c = edge_val(ep, f, E + e);
                atomicAdd(&hist[c >> NBBITS], 1);
            }
        }
        __syncthreads();
        if (tid < NBK_PAD) lofs[tid] = hist[tid];
        __syncthreads();
        for (int off = 1; off < NBK_PAD; off <<= 1) {
            int t = (tid < NBK_PAD && tid >= off) ? lofs[tid - off] : 0;
            __syncthreads();
            if (tid < NBK_PAD) lofs[tid] += t;
            __syncthreads();
        }
        if (tid < NBK_PAD) { lofs[tid] -= hist[tid]; hist[tid] = 0; }
        __syncthreads();
        for (int i = tid; i < PCH; i += 256) {
            long e = base + i;
            if (e < E) {
                int c = edge_val(ep, f, E + e);
                int r = edge_val(ep, f, e);
                int b = c >> NBBITS;
                int pos = lofs[b] + atomicAdd(&hist[b], 1);
                stage[pos] = (unsigned)r | ((unsigned)(c & ((1 << NBBITS) - 1)) << 17);
            }
        }
        __syncthreads();
        // bptr is a pure count array (memset 0); append offset is count-based
        if (tid < NBK_PAD && hist[tid]) gbase[tid] = atomicAdd(&bptr[tid], hist[tid]);
        __syncthreads();
        int wid = tid >> 6, lane = tid & 63;
        for (int b = wid; b < NBK_PAD; b += 4) {
            int c = hist[b];
            if (c == 0) continue;
            int lo = lofs[b], go = gbase[b];
            unsigned* dst = ebuf + (size_t)b * BCAPE + go;
            for (int j = lane; j < c; j += 64) dst[j] = stage[lo + j];
        }
    } else {
        // ---------------- gemm path: H1 = bf16(X @ W1) ----------------
        float* Ws = (float*)smraw;                // [64*64]
        float* Xs = (float*)(smraw + 16384);      // [32*68]
        int lane = tid & 63;
        int wv = tid >> 6;                        // wave 0..3
        for (int i = tid; i < 64 * 64; i += 256) Ws[i] = W[i];

        int bid = blockIdx.x - nPart;
        int ngb = gridDim.x - nPart;
        int ntiles = (N + 31) >> 5;
        for (int tile = bid; tile < ntiles; tile += ngb) {
            int rr = tid >> 4, c4 = tid & 15;     // rr 0..15; stage rr and rr+16
            int g0 = (tile << 5) + rr;
            int g1 = g0 + 16;
            float4 v0 = make_float4(0.f, 0.f, 0.f, 0.f);
            float4 v1 = make_float4(0.f, 0.f, 0.f, 0.f);
            if (g0 < N) v0 = *(const float4*)(x + (size_t)g0 * 64 + c4 * 4);
            if (g1 < N) v1 = *(const float4*)(x + (size_t)g1 * 64 + c4 * 4);
            __syncthreads();            // protects Ws (1st iter) + Xs reuse
            *(float4*)(&Xs[rr * 68 + c4 * 4]) = v0;
            *(float4*)(&Xs[(rr + 16) * 68 + c4 * 4]) = v1;
            __syncthreads();
            float acc[8];
            #pragma unroll
            for (int r = 0; r < 8; ++r) acc[r] = 0.f;
            int rbase = wv * 8;
            #pragma unroll 4
            for (int k4 = 0; k4 < 16; ++k4) {
                float w0 = Ws[(4 * k4 + 0) * 64 + lane];
                float w1 = Ws[(4 * k4 + 1) * 64 + lane];
                float w2 = Ws[(4 * k4 + 2) * 64 + lane];
                float w3 = Ws[(4 * k4 + 3) * 64 + lane];
                #pragma unroll
                for (int r = 0; r < 8; ++r) {
                    float4 xq = *(const float4*)(&Xs[(rbase + r) * 68 + k4 * 4]);
                    acc[r] = fmaf(xq.x, w0, acc[r]);
                    acc[r] = fmaf(xq.y, w1, acc[r]);
                    acc[r] = fmaf(xq.z, w2, acc[r]);
                    acc[r] = fmaf(xq.w, w3, acc[r]);
                }
            }
            int row0 = (tile << 5) + rbase;
            #pragma unroll
            for (int r = 0; r < 8; ++r) {
                int row = row0 + r;
                if (row < N) H[(size_t)row * 64 + lane] = f2b(acc[r]);
            }
        }
    }
}

// per-bucket exact CSR: bucket-base scan, degree hist, block scan ->
// offs/dinv, LDS slot assignment, srcA staged in LDS.
__global__ __launch_bounds__(1024) void k_bucket(const unsigned* __restrict__ ebuf,
                                                 const int* __restrict__ bptr,
                                                 int* __restrict__ offs,
                                                 float* __restrict__ dinv,
                                                 int* __restrict__ srcA, int N, int E) {
    __shared__ int hist[1024], escan[1024], wsum[16];
    __shared__ int bco[NBK_PAD];
    __shared__ int stage[BCAP];
    int tid = threadIdx.x, b = blockIdx.x;
    int lane = tid & 63, wid = tid >> 6;
    hist[tid] = 0;
    // redundant per-block exclusive scan of the 128 bucket counts
    if (tid < NBK_PAD) {
        int c = bptr[tid];
        int s = c;
        #pragma unroll
        for (int off = 1; off < 64; off <<= 1) {
            int t = __shfl(s, lane - off);
            if (lane >= off) s += t;
        }
        if (lane == 63) wsum[wid] = s;
        bco[tid] = s - c;               // exclusive within wave
    }
    if (tid == 0 && b == 0) offs[N] = E;
    __syncthreads();
    if (tid >= 64 && tid < NBK_PAD) bco[tid] += wsum[0];
    __syncthreads();

    int rbase = b * BCAPE;              // padded read region
    int lo = bco[b];                    // compact write base
    int m = bptr[b];                    // exact count
    for (int i = tid; i < m; i += 1024) {
        unsigned w = ebuf[rbase + i];
        atomicAdd(&hist[w >> 17], 1);
    }
    __syncthreads();
    int v = hist[tid];
    int s = v;
    #pragma unroll
    for (int off = 1; off < 64; off <<= 1) {
        int t = __shfl(s, lane - off);
        if (lane >= off) s += t;
    }
    if (lane == 63) wsum[wid] = s;
    __syncthreads();
    if (tid < 16) {
        int xv = wsum[tid];
        int ss = xv;
        #pragma unroll
        for (int off = 1; off < 16; off <<= 1) {
            int t = __shfl(ss, lane - off);
            if (lane >= off) ss += t;
        }
        wsum[tid] = ss - xv;            // exclusive among wave sums
    }
    __syncthreads();
    int excl = s - v + wsum[wid];
    escan[tid] = excl;
    int g = (b << NBBITS) + tid;
    if (g < N) {
        offs[g] = lo + excl;
        dinv[g] = rsqrtf((float)(v + 1));   // +1 self-loop
    }
    __syncthreads();
    for (int i = tid; i < m; i += 1024) {
        unsigned w = ebuf[rbase + i];
        int lc = w >> 17;
        int src = (int)(w & 0x1FFFFu);
        int sl = escan[lc] + atomicSub(&hist[lc], 1) - 1;
        if (sl < BCAP) stage[sl] = src;
        else srcA[lo + sl] = src;       // statistically-cold overflow path
    }
    __syncthreads();
    int mm = min(m, BCAP);
    for (int i = tid; i < mm; i += 1024) srcA[lo + i] = stage[i];
}

// Layer-1 aggregation: 8 nodes per wave (8-lane groups). Lane s of group g
// owns features 8s..8s+7 of node wid*8+g: private accumulation, no parity
// fold. Per j0-block: stage 8 (src, dinv) per group, broadcast via shfl,
// then 8 INDEPENDENT uint4 gathers issued before any consume (8-deep MLP).
// Fused with relu, bias, and the 64->2 GEMM of layer 2. Writes Z=[N,2].
__global__ void k_agg1(const unsigned short* __restrict__ H1,
                       const int* __restrict__ srcA,
                       const float* __restrict__ dinv, const int* __restrict__ offs,
                       const float* __restrict__ b1, const float* __restrict__ W2,
                       float* __restrict__ Z, int N) {
    int wid = (blockIdx.x * blockDim.x + threadIdx.x) >> 6;
    int lane = threadIdx.x & 63;
    int g = lane >> 3, s = lane & 7;
    int n = wid * 8 + g;
    bool nvalid = (n < N);
    int nn = nvalid ? n : 0;
    float dn = dinv[nn];
    int base = offs[nn];
    int cnt = nvalid ? (offs[nn + 1] - base) : 0;
    // wave-uniform loop bound: max degree over the 8 groups
    int cm = cnt;
    #pragma unroll
    for (int off = 8; off <= 32; off <<= 1) cm = max(cm, __shfl_xor(cm, off));
    float a[8];
    #pragma unroll
    for (int k = 0; k < 8; ++k) a[k] = 0.f;
    const uint4* H4 = (const uint4*)H1;   // row r = H4[r*8 + s]
    int gb = g << 3;
    for (int j0 = 0; j0 < cm; j0 += 8) {
        int sv = 0; float wl = 0.f;
        if (j0 + s < cnt) { sv = srcA[base + j0 + s]; wl = dinv[sv]; }
        int   s0 = __shfl(sv, gb + 0), s1 = __shfl(sv, gb + 1);
        int   s2 = __shfl(sv, gb + 2), s3 = __shfl(sv, gb + 3);
        int   s4 = __shfl(sv, gb + 4), s5 = __shfl(sv, gb + 5);
        int   s6 = __shfl(sv, gb + 6), s7 = __shfl(sv, gb + 7);
        float w0 = __shfl(wl, gb + 0), w1 = __shfl(wl, gb + 1);
        float w2 = __shfl(wl, gb + 2), w3 = __shfl(wl, gb + 3);
        float w4 = __shfl(wl, gb + 4), w5 = __shfl(wl, gb + 5);
        float w6 = __shfl(wl, gb + 6), w7 = __shfl(wl, gb + 7);
        uint4 r0 = H4[(size_t)s0 * 8 + s];
        uint4 r1 = H4[(size_t)s1 * 8 + s];
        uint4 r2 = H4[(size_t)s2 * 8 + s];
        uint4 r3 = H4[(size_t)s3 * 8 + s];
        uint4 r4 = H4[(size_t)s4 * 8 + s];
        uint4 r5 = H4[(size_t)s5 * 8 + s];
        uint4 r6 = H4[(size_t)s6 * 8 + s];
        uint4 r7 = H4[(size_t)s7 * 8 + s];
        acc8(a, r0, w0); acc8(a, r1, w1); acc8(a, r2, w2); acc8(a, r3, w3);
        acc8(a, r4, w4); acc8(a, r5, w5); acc8(a, r6, w6); acc8(a, r7, w7);
    }
    // self-loop term
    uint4 rs = H4[(size_t)nn * 8 + s];
    acc8(a, rs, dn);
    float4 b1a = *(const float4*)(b1 + s * 8);
    float4 b1b = *(const float4*)(b1 + s * 8 + 4);
    float h0 = fmaxf(dn * a[0] + b1a.x, 0.f);
    float h1 = fmaxf(dn * a[1] + b1a.y, 0.f);
    float h2 = fmaxf(dn * a[2] + b1a.z, 0.f);
    float h3 = fmaxf(dn * a[3] + b1a.w, 0.f);
    float h4 = fmaxf(dn * a[4] + b1b.x, 0.f);
    float h5 = fmaxf(dn * a[5] + b1b.y, 0.f);
    float h6 = fmaxf(dn * a[6] + b1b.z, 0.f);
    float h7 = fmaxf(dn * a[7] + b1b.w, 0.f);
    const float4* w2p = (const float4*)(W2 + s * 16);
    float4 q0 = w2p[0], q1 = w2p[1], q2 = w2p[2], q3 = w2p[3];
    float p0 = h0 * q0.x + h1 * q0.z + h2 * q1.x + h3 * q1.z
             + h4 * q2.x + h5 * q2.z + h6 * q3.x + h7 * q3.z;
    float p1 = h0 * q0.y + h1 * q0.w + h2 * q1.y + h3 * q1.w
             + h4 * q2.y + h5 * q2.w + h6 * q3.y + h7 * q3.w;
    // sum the 8 feature-octs within this group (xor stays inside the group)
    #pragma unroll
    for (int off = 1; off < 8; off <<= 1) {
        p0 += __shfl_xor(p0, off);
        p1 += __shfl_xor(p1, off);
    }
    if (s == 0 && nvalid) { Z[n * 2 + 0] = p0; Z[n * 2 + 1] = p1; }
}

// Layer-2 aggregation over Z=[N,2]: 4 nodes per wave (avg degree 16 -> full
// lane utilization), 16 lanes over neighbors per node.
__global__ void k_agg2(const float* __restrict__ Z, const int* __restrict__ srcA,
                       const float* __restrict__ dinv, const int* __restrict__ offs,
                       const float* __restrict__ b2, float* __restrict__ out, int N) {
    int t = blockIdx.x * blockDim.x + threadIdx.x;
    int lane = threadIdx.x & 63;
    int n = (t >> 6) * 4 + (lane >> 4);
    int sl = lane & 15;
    if (n >= N) return;                 // uniform per 16-lane group
    int base = offs[n];
    int cnt = offs[n + 1] - base;
    float a0 = 0.f, a1 = 0.f;
    const float2* Z2 = (const float2*)Z;
    for (int i = sl; i < cnt; i += 16) {
        int src = srcA[base + i];
        float w = dinv[src];
        float2 zv = Z2[src];
        a0 += w * zv.x;
        a1 += w * zv.y;
    }
    #pragma unroll
    for (int off = 8; off > 0; off >>= 1) {
        a0 += __shfl_xor(a0, off);
        a1 += __shfl_xor(a1, off);
    }
    if (sl == 0) {
        float dn = dinv[n];
        float2 zs = Z2[n];
        out[n * 2 + 0] = dn * (a0 + dn * zs.x) + b2[0];
        out[n * 2 + 1] = dn * (a1 + dn * zs.y) + b2[1];
    }
}

extern "C" void kernel_launch(void* const* d_in, const int* in_sizes, int n_in,
                              void* d_out, int out_size, void* d_ws, size_t ws_size,
                              hipStream_t stream) {
    const float* x  = (const float*)d_in[0];
    const int*   ep = (const int*)d_in[1];
    const float* W1 = (const float*)d_in[2];
    const float* b1 = (const float*)d_in[3];
    const float* W2 = (const float*)d_in[4];
    const float* b2 = (const float*)d_in[5];
    float* out = (float*)d_out;

    const int N = in_sizes[0] / D_IN;   // 100000
    const int E = in_sizes[1] / 2;      // 1600000

    char* ws = (char*)d_ws;
    size_t o = 0;
    auto alloc = [&](size_t bytes) {
        size_t r = o;
        o = (o + bytes + 255) & ~(size_t)255;
        return r;
    };
    int*            bptr  = (int*)           (ws + alloc(NBK_PAD * 4));
    float*          dinv  = (float*)         (ws + alloc((size_t)N * 4));
    int*            offs  = (int*)           (ws + alloc((size_t)(N + 1) * 4));
    unsigned*       ebuf  = (unsigned*)      (ws + alloc((size_t)NBK_PAD * BCAPE * 4));
    int*            srcA  = (int*)           (ws + alloc((size_t)E * 4));
    unsigned short* H1    = (unsigned short*)(ws + alloc((size_t)N * 64 * 2));
    float*          Z     = (float*)         (ws + alloc((size_t)N * 2 * 4));

    const int nbk = (N + (1 << NBBITS) - 1) >> NBBITS;   // 98
    const int nPart = (E + PCH - 1) / PCH;               // 196
    const int nGemm = 1024;

    (void)hipMemsetAsync(bptr, 0, NBK_PAD * sizeof(int), stream);
    k_part_gemm<<<nPart + nGemm, 256, 0, stream>>>(ep, bptr, ebuf, x, W1, H1, E, N, nPart);
    k_bucket<<<nbk, 1024, 0, stream>>>(ebuf, bptr, offs, dinv, srcA, N, E);
    // 8 nodes per wave -> ceil(N/8) waves -> /4 waves per block
    int nwav = (N + 7) / 8;
    k_agg1<<<(nwav + 3) / 4, 256, 0, stream>>>(H1, srcA, dinv, offs, b1, W2, Z, N);
    k_agg2<<<(N + 15) / 16, 256, 0, stream>>>(Z, srcA, dinv, offs, b2, out, N);
}

// Round 4
// 104.503 us; speedup vs baseline: 1.5597x; 1.0151x over previous
//
#include <hip/hip_runtime.h>

// GCN 2-layer: out = Ahat * relu(Ahat*(X W1)+b1) * W2 + b2
// Ahat = D^-1/2 (A+I) D^-1/2, pull-based CSR aggregation.
// R11: k_part_gemm restructured for latency hiding. R10 showed 46 us @ 24%
//     occupancy: gemm blocks drained in ~5 us, leaving 196 part blocks at
//     1 wave/SIMD, each a chain of unhidden global loads + LDS atomics.
//     Now: 1024-thread blocks (4 waves/SIMD part work), edges loaded ONCE
//     into registers via coalesced uint4 (8 edges/thread; row loads issued
//     before the scan so they complete under the barriers), 2-wave shfl
//     scan (3 barriers, was 14), 128-row gemm tiles. launch_bounds(1024,8)
//     caps VGPR at 64 -> 2 blocks/CU so all 316 gemm blocks run at t=0.

#define D_IN 64
#define NBBITS 10          // 1024 nodes per bucket
#define NBK_PAD 128        // padded bucket count (N=100K -> 98 real buckets)
#define PCH 8192           // edges per part block
#define BCAP 16384         // LDS srcA stage capacity per bucket
#define BCAPE 24576        // padded ebuf capacity per bucket (mean 16.3K, sd 128)

// ---- bf16 helpers (RN-even) ----
__device__ __forceinline__ float b2f(unsigned short u) {
    unsigned v = ((unsigned)u) << 16;
    float f;
    __builtin_memcpy(&f, &v, 4);
    return f;
}
__device__ __forceinline__ unsigned short f2b(float f) {
    unsigned u;
    __builtin_memcpy(&u, &f, 4);
    u += 0x7FFFu + ((u >> 16) & 1u);
    return (unsigned short)(u >> 16);
}

// edge_index may arrive as int64 (reference dtype) or int32 (harness note).
// int64 little-endian with values < 2^31 has all-zero odd 32-bit words.
__device__ __forceinline__ int edge_val(const int* __restrict__ p, int f64, long pos) {
    return f64 ? p[2 * pos] : p[pos];
}

// accumulate 8 bf16 features (one uint4) scaled by wgt into a[0..7]
__device__ __forceinline__ void acc8(float* a, uint4 rv, float wgt) {
    a[0] = fmaf(wgt, b2f((unsigned short)(rv.x & 0xFFFFu)), a[0]);
    a[1] = fmaf(wgt, b2f((unsigned short)(rv.x >> 16)), a[1]);
    a[2] = fmaf(wgt, b2f((unsigned short)(rv.y & 0xFFFFu)), a[2]);
    a[3] = fmaf(wgt, b2f((unsigned short)(rv.y >> 16)), a[3]);
    a[4] = fmaf(wgt, b2f((unsigned short)(rv.z & 0xFFFFu)), a[4]);
    a[5] = fmaf(wgt, b2f((unsigned short)(rv.z >> 16)), a[5]);
    a[6] = fmaf(wgt, b2f((unsigned short)(rv.w & 0xFFFFu)), a[6]);
    a[7] = fmaf(wgt, b2f((unsigned short)(rv.w >> 16)), a[7]);
}

// Fat kernel: blocks [0, nPart) partition edges (counting sort into padded
// per-bucket regions); blocks [nPart, grid) do H1 = bf16(X @ W1).
__global__ __launch_bounds__(1024, 8) void k_part_gemm(
        const int* __restrict__ ep, int* __restrict__ bptr,
        unsigned* __restrict__ ebuf,
        const float* __restrict__ x, const float* __restrict__ W,
        unsigned short* __restrict__ H, int E, int N, int nPart) {
    __shared__ __align__(16) char smraw[51200];
    int tid = threadIdx.x;
    int lane = tid & 63;

    if (blockIdx.x < nPart) {
        // ---------------- partition path ----------------
        int* hist  = (int*)smraw;                 // [128]
        int* lofs  = hist + NBK_PAD;              // [128]
        int* gbase = lofs + NBK_PAD;              // [128]
        int* fsh   = gbase + NBK_PAD;             // [4]: flag, wsum0, wsum1
        unsigned* stage = (unsigned*)(fsh + 4);   // [PCH], 16B-aligned

        if (tid < NBK_PAD) hist[tid] = 0;
        // per-block dtype detect (8 KB redundant read, L2-shared)
        if (tid < 64) {
            int bad = 0;
            for (int i = tid; i < 1024; i += 64)
                if (ep[2 * i + 1] != 0) bad = 1;
            unsigned long long m = __ballot(bad);
            if (tid == 0) fsh[0] = (m == 0ull) ? 1 : 0;   // 1 => int64
        }
        __syncthreads();
        int f = fsh[0];
        long base = (long)blockIdx.x * PCH;
        long rem64 = (long)E - base;
        int nE = rem64 > PCH ? PCH : (int)rem64;
        int j0 = tid * 8;                 // this thread's 8 local edges
        int nv = nE - j0;
        nv = nv < 0 ? 0 : (nv > 8 ? 8 : nv);
        unsigned cc[8], rr2[8];
        #pragma unroll
        for (int k = 0; k < 8; ++k) { cc[k] = 0; rr2[k] = 0; }
        bool fullv = (nv == 8);
        const uint4* p4 = (const uint4*)ep;
        // ---- load 8 cols into registers (coalesced uint4 when aligned) ----
        if (f) {
            if (fullv && ((E & 1) == 0)) {
                size_t cb = ((size_t)E + (size_t)base + j0) >> 1;   // uint4 idx
                uint4 a0 = p4[cb + 0], a1 = p4[cb + 1];
                uint4 a2 = p4[cb + 2], a3 = p4[cb + 3];
                cc[0] = a0.x; cc[1] = a0.z; cc[2] = a1.x; cc[3] = a1.z;
                cc[4] = a2.x; cc[5] = a2.z; cc[6] = a3.x; cc[7] = a3.z;
            } else {
                for (int k = 0; k < 8; ++k)
                    if (k < nv) cc[k] = (unsigned)ep[2 * ((size_t)E + base + j0 + k)];
            }
        } else {
            if (fullv && ((E & 3) == 0)) {
                size_t cb = ((size_t)E + (size_t)base + j0) >> 2;
                uint4 a0 = p4[cb + 0], a1 = p4[cb + 1];
                cc[0] = a0.x; cc[1] = a0.y; cc[2] = a0.z; cc[3] = a0.w;
                cc[4] = a1.x; cc[5] = a1.y; cc[6] = a1.z; cc[7] = a1.w;
            } else {
                for (int k = 0; k < 8; ++k)
                    if (k < nv) cc[k] = (unsigned)ep[(size_t)E + base + j0 + k];
            }
        }
        // histogram
        #pragma unroll
        for (int k = 0; k < 8; ++k)
            if (k < nv) atomicAdd(&hist[cc[k] >> NBBITS], 1);
        // ---- issue row loads now; they drain under the scan barriers ----
        if (f) {
            if (fullv && ((E & 1) == 0)) {
                size_t rb = ((size_t)base + j0) >> 1;
                uint4 b0 = p4[rb + 0], b1 = p4[rb + 1];
                uint4 b2 = p4[rb + 2], b3 = p4[rb + 3];
                rr2[0] = b0.x; rr2[1] = b0.z; rr2[2] = b1.x; rr2[3] = b1.z;
                rr2[4] = b2.x; rr2[5] = b2.z; rr2[6] = b3.x; rr2[7] = b3.z;
            } else {
                for (int k = 0; k < 8; ++k)
                    if (k < nv) rr2[k] = (unsigned)ep[2 * ((size_t)base + j0 + k)];
            }
        } else {
            if (fullv && ((E & 3) == 0)) {
                size_t rb = ((size_t)base + j0) >> 2;
                uint4 b0 = p4[rb + 0], b1 = p4[rb + 1];
                rr2[0] = b0.x; rr2[1] = b0.y; rr2[2] = b0.z; rr2[3] = b0.w;
                rr2[4] = b1.x; rr2[5] = b1.y; rr2[6] = b1.z; rr2[7] = b1.w;
            } else {
                for (int k = 0; k < 8; ++k)
                    if (k < nv) rr2[k] = (unsigned)ep[(size_t)base + j0 + k];
            }
        }
        __syncthreads();
        // ---- 128-entry exclusive scan via 2-wave shfl ----
        if (tid < NBK_PAD) {
            int c = hist[tid], s = c;
            #pragma unroll
            for (int off = 1; off < 64; off <<= 1) {
                int t2 = __shfl(s, lane - off);
                if (lane >= off) s += t2;
            }
            if (lane == 63) fsh[1 + (tid >> 6)] = s;
            lofs[tid] = s - c;
        }
        __syncthreads();
        if (tid >= 64 && tid < NBK_PAD) lofs[tid] += fsh[1];
        if (tid < NBK_PAD) hist[tid] = 0;
        __syncthreads();
        // ---- scatter into LDS stage (register-resident edges) ----
        #pragma unroll
        for (int k = 0; k < 8; ++k) {
            if (k < nv) {
                unsigned c = cc[k];
                int b = c >> NBBITS;
                int pos = lofs[b] + atomicAdd(&hist[b], 1);
                stage[pos] = rr2[k] | ((c & ((1u << NBBITS) - 1)) << 17);
            }
        }
        __syncthreads();
        // bptr is a pure count array (memset 0); append offset is count-based
        if (tid < NBK_PAD && hist[tid]) gbase[tid] = atomicAdd(&bptr[tid], hist[tid]);
        __syncthreads();
        // coalesced burst flush: 16 waves x 8 buckets
        int wv = tid >> 6;
        for (int b = wv; b < NBK_PAD; b += 16) {
            int c = hist[b];
            if (c == 0) continue;
            int lo = lofs[b], go = gbase[b];
            unsigned* dst = ebuf + (size_t)b * BCAPE + go;
            for (int j = lane; j < c; j += 64) dst[j] = stage[lo + j];
        }
    } else {
        // ---------------- gemm path: H1 = bf16(X @ W1), 128-row tiles ----
        float* Ws = (float*)smraw;                // [64*64] = 16384 B
        float* Xs = (float*)(smraw + 16384);      // [128*68] = 34816 B
        int wv = tid >> 6;                        // wave 0..15
        for (int i = tid; i < 64 * 64; i += 1024) Ws[i] = W[i];

        int bid = blockIdx.x - nPart;
        int ngb = gridDim.x - nPart;
        int ntiles = (N + 127) >> 7;
        for (int tile = bid; tile < ntiles; tile += ngb) {
            int rr = tid >> 4, c4 = tid & 15;     // rr 0..63; stage rr and rr+64
            int g0 = (tile << 7) + rr;
            int g1 = g0 + 64;
            float4 v0 = make_float4(0.f, 0.f, 0.f, 0.f);
            float4 v1 = make_float4(0.f, 0.f, 0.f, 0.f);
            if (g0 < N) v0 = *(const float4*)(x + (size_t)g0 * 64 + c4 * 4);
            if (g1 < N) v1 = *(const float4*)(x + (size_t)g1 * 64 + c4 * 4);
            __syncthreads();            // protects Ws (1st iter) + Xs reuse
            *(float4*)(&Xs[rr * 68 + c4 * 4]) = v0;
            *(float4*)(&Xs[(rr + 64) * 68 + c4 * 4]) = v1;
            __syncthreads();
            float acc[8];
            #pragma unroll
            for (int r = 0; r < 8; ++r) acc[r] = 0.f;
            int rbase = wv * 8;
            #pragma unroll 4
            for (int k4 = 0; k4 < 16; ++k4) {
                float w0 = Ws[(4 * k4 + 0) * 64 + lane];
                float w1 = Ws[(4 * k4 + 1) * 64 + lane];
                float w2 = Ws[(4 * k4 + 2) * 64 + lane];
                float w3 = Ws[(4 * k4 + 3) * 64 + lane];
                #pragma unroll
                for (int r = 0; r < 8; ++r) {
                    float4 xq = *(const float4*)(&Xs[(rbase + r) * 68 + k4 * 4]);
                    acc[r] = fmaf(xq.x, w0, acc[r]);
                    acc[r] = fmaf(xq.y, w1, acc[r]);
                    acc[r] = fmaf(xq.z, w2, acc[r]);
                    acc[r] = fmaf(xq.w, w3, acc[r]);
                }
            }
            int row0 = (tile << 7) + rbase;
            #pragma unroll
            for (int r = 0; r < 8; ++r) {
                int row = row0 + r;
                if (row < N) H[(size_t)row * 64 + lane] = f2b(acc[r]);
            }
        }
    }
}

// per-bucket exact CSR: bucket-base scan, degree hist, block scan ->
// offs/dinv, LDS slot assignment, srcA staged in LDS.
__global__ __launch_bounds__(1024) void k_bucket(const unsigned* __restrict__ ebuf,
                                                 const int* __restrict__ bptr,
                                                 int* __restrict__ offs,
                                                 float* __restrict__ dinv,
                                                 int* __restrict__ srcA, int N, int E) {
    __shared__ int hist[1024], escan[1024], wsum[16];
    __shared__ int bco[NBK_PAD];
    __shared__ int stage[BCAP];
    int tid = threadIdx.x, b = blockIdx.x;
    int lane = tid & 63, wid = tid >> 6;
    hist[tid] = 0;
    // redundant per-block exclusive scan of the 128 bucket counts
    if (tid < NBK_PAD) {
        int c = bptr[tid];
        int s = c;
        #pragma unroll
        for (int off = 1; off < 64; off <<= 1) {
            int t = __shfl(s, lane - off);
            if (lane >= off) s += t;
        }
        if (lane == 63) wsum[wid] = s;
        bco[tid] = s - c;               // exclusive within wave
    }
    if (tid == 0 && b == 0) offs[N] = E;
    __syncthreads();
    if (tid >= 64 && tid < NBK_PAD) bco[tid] += wsum[0];
    __syncthreads();

    int rbase = b * BCAPE;              // padded read region
    int lo = bco[b];                    // compact write base
    int m = bptr[b];                    // exact count
    for (int i = tid; i < m; i += 1024) {
        unsigned w = ebuf[rbase + i];
        atomicAdd(&hist[w >> 17], 1);
    }
    __syncthreads();
    int v = hist[tid];
    int s = v;
    #pragma unroll
    for (int off = 1; off < 64; off <<= 1) {
        int t = __shfl(s, lane - off);
        if (lane >= off) s += t;
    }
    if (lane == 63) wsum[wid] = s;
    __syncthreads();
    if (tid < 16) {
        int xv = wsum[tid];
        int ss = xv;
        #pragma unroll
        for (int off = 1; off < 16; off <<= 1) {
            int t = __shfl(ss, lane - off);
            if (lane >= off) ss += t;
        }
        wsum[tid] = ss - xv;            // exclusive among wave sums
    }
    __syncthreads();
    int excl = s - v + wsum[wid];
    escan[tid] = excl;
    int g = (b << NBBITS) + tid;
    if (g < N) {
        offs[g] = lo + excl;
        dinv[g] = rsqrtf((float)(v + 1));   // +1 self-loop
    }
    __syncthreads();
    for (int i = tid; i < m; i += 1024) {
        unsigned w = ebuf[rbase + i];
        int lc = w >> 17;
        int src = (int)(w & 0x1FFFFu);
        int sl = escan[lc] + atomicSub(&hist[lc], 1) - 1;
        if (sl < BCAP) stage[sl] = src;
        else srcA[lo + sl] = src;       // statistically-cold overflow path
    }
    __syncthreads();
    int mm = min(m, BCAP);
    for (int i = tid; i < mm; i += 1024) srcA[lo + i] = stage[i];
}

// Layer-1 aggregation: 8 nodes per wave (8-lane groups). Lane s of group g
// owns features 8s..8s+7 of node wid*8+g: private accumulation, no parity
// fold. Per j0-block: stage 8 (src, dinv) per group, broadcast via shfl,
// then 8 INDEPENDENT uint4 gathers issued before any consume (8-deep MLP).
// Fused with relu, bias, and the 64->2 GEMM of layer 2. Writes Z=[N,2].
__global__ void k_agg1(const unsigned short* __restrict__ H1,
                       const int* __restrict__ srcA,
                       const float* __restrict__ dinv, const int* __restrict__ offs,
                       const float* __restrict__ b1, const float* __restrict__ W2,
                       float* __restrict__ Z, int N) {
    int wid = (blockIdx.x * blockDim.x + threadIdx.x) >> 6;
    int lane = threadIdx.x & 63;
    int g = lane >> 3, s = lane & 7;
    int n = wid * 8 + g;
    bool nvalid = (n < N);
    int nn = nvalid ? n : 0;
    float dn = dinv[nn];
    int base = offs[nn];
    int cnt = nvalid ? (offs[nn + 1] - base) : 0;
    // wave-uniform loop bound: max degree over the 8 groups
    int cm = cnt;
    #pragma unroll
    for (int off = 8; off <= 32; off <<= 1) cm = max(cm, __shfl_xor(cm, off));
    float a[8];
    #pragma unroll
    for (int k = 0; k < 8; ++k) a[k] = 0.f;
    const uint4* H4 = (const uint4*)H1;   // row r = H4[r*8 + s]
    int gb = g << 3;
    for (int j0 = 0; j0 < cm; j0 += 8) {
        int sv = 0; float wl = 0.f;
        if (j0 + s < cnt) { sv = srcA[base + j0 + s]; wl = dinv[sv]; }
        int   s0 = __shfl(sv, gb + 0), s1 = __shfl(sv, gb + 1);
        int   s2 = __shfl(sv, gb + 2), s3 = __shfl(sv, gb + 3);
        int   s4 = __shfl(sv, gb + 4), s5 = __shfl(sv, gb + 5);
        int   s6 = __shfl(sv, gb + 6), s7 = __shfl(sv, gb + 7);
        float w0 = __shfl(wl, gb + 0), w1 = __shfl(wl, gb + 1);
        float w2 = __shfl(wl, gb + 2), w3 = __shfl(wl, gb + 3);
        float w4 = __shfl(wl, gb + 4), w5 = __shfl(wl, gb + 5);
        float w6 = __shfl(wl, gb + 6), w7 = __shfl(wl, gb + 7);
        uint4 r0 = H4[(size_t)s0 * 8 + s];
        uint4 r1 = H4[(size_t)s1 * 8 + s];
        uint4 r2 = H4[(size_t)s2 * 8 + s];
        uint4 r3 = H4[(size_t)s3 * 8 + s];
        uint4 r4 = H4[(size_t)s4 * 8 + s];
        uint4 r5 = H4[(size_t)s5 * 8 + s];
        uint4 r6 = H4[(size_t)s6 * 8 + s];
        uint4 r7 = H4[(size_t)s7 * 8 + s];
        acc8(a, r0, w0); acc8(a, r1, w1); acc8(a, r2, w2); acc8(a, r3, w3);
        acc8(a, r4, w4); acc8(a, r5, w5); acc8(a, r6, w6); acc8(a, r7, w7);
    }
    // self-loop term
    uint4 rs = H4[(size_t)nn * 8 + s];
    acc8(a, rs, dn);
    float4 b1a = *(const float4*)(b1 + s * 8);
    float4 b1b = *(const float4*)(b1 + s * 8 + 4);
    float h0 = fmaxf(dn * a[0] + b1a.x, 0.f);
    float h1 = fmaxf(dn * a[1] + b1a.y, 0.f);
    float h2 = fmaxf(dn * a[2] + b1a.z, 0.f);
    float h3 = fmaxf(dn * a[3] + b1a.w, 0.f);
    float h4 = fmaxf(dn * a[4] + b1b.x, 0.f);
    float h5 = fmaxf(dn * a[5] + b1b.y, 0.f);
    float h6 = fmaxf(dn * a[6] + b1b.z, 0.f);
    float h7 = fmaxf(dn * a[7] + b1b.w, 0.f);
    const float4* w2p = (const float4*)(W2 + s * 16);
    float4 q0 = w2p[0], q1 = w2p[1], q2 = w2p[2], q3 = w2p[3];
    float p0 = h0 * q0.x + h1 * q0.z + h2 * q1.x + h3 * q1.z
             + h4 * q2.x + h5 * q2.z + h6 * q3.x + h7 * q3.z;
    float p1 = h0 * q0.y + h1 * q0.w + h2 * q1.y + h3 * q1.w
             + h4 * q2.y + h5 * q2.w + h6 * q3.y + h7 * q3.w;
    // sum the 8 feature-octs within this group (xor stays inside the group)
    #pragma unroll
    for (int off = 1; off < 8; off <<= 1) {
        p0 += __shfl_xor(p0, off);
        p1 += __shfl_xor(p1, off);
    }
    if (s == 0 && nvalid) { Z[n * 2 + 0] = p0; Z[n * 2 + 1] = p1; }
}

// Layer-2 aggregation over Z=[N,2]: 4 nodes per wave (avg degree 16 -> full
// lane utilization), 16 lanes over neighbors per node.
__global__ void k_agg2(const float* __restrict__ Z, const int* __restrict__ srcA,
                       const float* __restrict__ dinv, const int* __restrict__ offs,
                       const float* __restrict__ b2, float* __restrict__ out, int N) {
    int t = blockIdx.x * blockDim.x + threadIdx.x;
    int lane = threadIdx.x & 63;
    int n = (t >> 6) * 4 + (lane >> 4);
    int sl = lane & 15;
    if (n >= N) return;                 // uniform per 16-lane group
    int base = offs[n];
    int cnt = offs[n + 1] - base;
    float a0 = 0.f, a1 = 0.f;
    const float2* Z2 = (const float2*)Z;
    for (int i = sl; i < cnt; i += 16) {
        int src = srcA[base + i];
        float w = dinv[src];
        float2 zv = Z2[src];
        a0 += w * zv.x;
        a1 += w * zv.y;
    }
    #pragma unroll
    for (int off = 8; off > 0; off >>= 1) {
        a0 += __shfl_xor(a0, off);
        a1 += __shfl_xor(a1, off);
    }
    if (sl == 0) {
        float dn = dinv[n];
        float2 zs = Z2[n];
        out[n * 2 + 0] = dn * (a0 + dn * zs.x) + b2[0];
        out[n * 2 + 1] = dn * (a1 + dn * zs.y) + b2[1];
    }
}

extern "C" void kernel_launch(void* const* d_in, const int* in_sizes, int n_in,
                              void* d_out, int out_size, void* d_ws, size_t ws_size,
                              hipStream_t stream) {
    const float* x  = (const float*)d_in[0];
    const int*   ep = (const int*)d_in[1];
    const float* W1 = (const float*)d_in[2];
    const float* b1 = (const float*)d_in[3];
    const float* W2 = (const float*)d_in[4];
    const float* b2 = (const float*)d_in[5];
    float* out = (float*)d_out;

    const int N = in_sizes[0] / D_IN;   // 100000
    const int E = in_sizes[1] / 2;      // 1600000

    char* ws = (char*)d_ws;
    size_t o = 0;
    auto alloc = [&](size_t bytes) {
        size_t r = o;
        o = (o + bytes + 255) & ~(size_t)255;
        return r;
    };
    int*            bptr  = (int*)           (ws + alloc(NBK_PAD * 4));
    float*          dinv  = (float*)         (ws + alloc((size_t)N * 4));
    int*            offs  = (int*)           (ws + alloc((size_t)(N + 1) * 4));
    unsigned*       ebuf  = (unsigned*)      (ws + alloc((size_t)NBK_PAD * BCAPE * 4));
    int*            srcA  = (int*)           (ws + alloc((size_t)E * 4));
    unsigned short* H1    = (unsigned short*)(ws + alloc((size_t)N * 64 * 2));
    float*          Z     = (float*)         (ws + alloc((size_t)N * 2 * 4));

    const int nbk = (N + (1 << NBBITS) - 1) >> NBBITS;   // 98
    const int nPart = (E + PCH - 1) / PCH;               // 196
    int nGemm = 512 - nPart;                             // 2 blocks/CU co-resident
    if (nGemm < 64) nGemm = 64;

    (void)hipMemsetAsync(bptr, 0, NBK_PAD * sizeof(int), stream);
    k_part_gemm<<<nPart + nGemm, 1024, 0, stream>>>(ep, bptr, ebuf, x, W1, H1, E, N, nPart);
    k_bucket<<<nbk, 1024, 0, stream>>>(ebuf, bptr, offs, dinv, srcA, N, E);
    // 8 nodes per wave -> ceil(N/8) waves -> /4 waves per block
    int nwav = (N + 7) / 8;
    k_agg1<<<(nwav + 3) / 4, 256, 0, stream>>>(H1, srcA, dinv, offs, b1, W2, Z, N);
    k_agg2<<<(N + 15) / 16, 256, 0, stream>>>(Z, srcA, dinv, offs, b2, out, N);
}